// Round 2
// baseline (1006.462 us; speedup 1.0000x reference)
//
#include <hip/hip_runtime.h>

typedef __attribute__((ext_vector_type(8)))  short bf16x8;   // 8 bf16 = 4 VGPR MFMA operand
typedef __attribute__((ext_vector_type(16))) float f32x16;   // 32x32 MFMA accumulator

__device__ __forceinline__ short f2bf(float f){
    unsigned int u = __builtin_bit_cast(unsigned int, f);
    u += 0x7fffu + ((u >> 16) & 1u);           // RNE, no NaN inputs here
    return (short)(u >> 16);
}
__device__ __forceinline__ float bf2f(short s){
    unsigned int u = ((unsigned int)(unsigned short)s) << 16;
    return __builtin_bit_cast(float, u);
}

// ---------------- prep: weights -> bf16 Wt[e(9)][tap(9)][cout(32)][cin(32)] ----------------
__global__ __launch_bounds__(256) void prep_weights(const float* __restrict__ ew,
                                                    const float* __restrict__ sw,
                                                    short* __restrict__ wt){
    int i = blockIdx.x * 256 + threadIdx.x;
    if(i >= 9*9*32*32) return;
    int ci = i & 31;
    int co = (i >> 5) & 31;
    int tp = (i >> 10) % 9;
    int e  = (i >> 10) / 9;
    float v = (e < 8) ? ew[(((e*32 + co)*32 + ci)*9) + tp]
                      : sw[((co*32 + ci)*9) + tp];
    wt[i] = f2bf(v);
}

// ---------------- gate: fp32 conv -> sigmoid -> top2 -> softmax -> dense route (bf16 x8/px) ----------------
// Selection robustness: if biased-score margin between rank2 and rank3 is < 1e-4
// (≈50x worst-case fp32 conv rounding), recompute that pixel's scores in fp64.
// Rank1<->rank2 swaps are harmless (dense combine is symmetric in k).
__global__ __launch_bounds__(256) void gate_kernel(const float* __restrict__ x,
                                                   const float* __restrict__ gw,
                                                   const float* __restrict__ gb,
                                                   short* __restrict__ route){
    int wg = blockIdx.x;                    // 512 = 8 images * 64 row-tiles(4 rows)
    int b  = wg >> 6;
    int y  = (wg & 63) * 4 + (threadIdx.x >> 6);
    int xb = (threadIdx.x & 63) * 4;        // thread: 4 consecutive px in one row
    const float* xim = x + (size_t)b * (32*256*256);

    float g[8][4];
    #pragma unroll
    for(int e=0;e<8;e++){
        #pragma unroll
        for(int p=0;p<4;p++) g[e][p] = 0.f;
    }
    for(int ci=0; ci<32; ++ci){
        #pragma unroll
        for(int kh=0; kh<3; ++kh){
            int yy = y + kh - 1;
            float seg[6];
            if(yy >= 0 && yy < 256){
                const float* xr = xim + ((size_t)ci*256 + yy)*256;
                #pragma unroll
                for(int j=0;j<6;j++){
                    int xx = xb - 1 + j;
                    seg[j] = (xx >= 0 && xx < 256) ? xr[xx] : 0.f;
                }
            } else {
                #pragma unroll
                for(int j=0;j<6;j++) seg[j] = 0.f;
            }
            const float* gwp = gw + (ci*3 + kh)*3;     // gw[e][ci][kh][kw], e-stride 288
            #pragma unroll
            for(int kw=0; kw<3; ++kw){
                #pragma unroll
                for(int e=0;e<8;e++){
                    float wv = gwp[e*288 + kw];
                    #pragma unroll
                    for(int p=0;p<4;p++) g[e][p] = fmaf(seg[p+kw], wv, g[e][p]);
                }
            }
        }
    }
    size_t pixbase = (size_t)(b*256 + y)*256 + xb;
    #pragma unroll
    for(int p=0;p<4;p++){
        float v1b=-1e30f, v2b=-1e30f, v3b=-1e30f, r1=0.f, r2=0.f; int i1=-1, i2=-1;
        #pragma unroll
        for(int e=0;e<8;e++){
            float se = 1.f/(1.f + expf(-g[e][p]));     // raw score
            float be = se + gb[e];                     // biased (selection only)
            if(be > v1b){ v3b=v2b; v2b=v1b; r2=r1; i2=i1; v1b=be; r1=se; i1=e; }
            else if(be > v2b){ v3b=v2b; v2b=be; r2=se; i2=e; }
            else if(be > v3b){ v3b=be; }
        }
        if(v2b - v3b < 1e-4f){
            // fp64 recompute of this pixel's 8 scores + reselect
            double gd[8];
            #pragma unroll
            for(int e=0;e<8;e++) gd[e] = 0.0;
            for(int ci=0; ci<32; ++ci){
                for(int kh=0; kh<3; ++kh){
                    int yy = y + kh - 1;
                    if(yy < 0 || yy >= 256) continue;
                    const float* xr = xim + ((size_t)ci*256 + yy)*256;
                    for(int kw=0; kw<3; ++kw){
                        int xx = xb + p + kw - 1;
                        if(xx < 0 || xx >= 256) continue;
                        double xv = (double)xr[xx];
                        const float* gwp = gw + ci*9 + kh*3 + kw;
                        #pragma unroll
                        for(int e=0;e<8;e++) gd[e] += xv * (double)gwp[e*288];
                    }
                }
            }
            double b1=-1e30, b2=-1e30; double rr1=0.0, rr2=0.0; int j1=-1, j2=-1;
            #pragma unroll
            for(int e=0;e<8;e++){
                double sd = 1.0/(1.0 + exp(-gd[e]));
                double bd = sd + (double)gb[e];
                if(bd > b1){ b2=b1; rr2=rr1; j2=j1; b1=bd; rr1=sd; j1=e; }
                else if(bd > b2){ b2=bd; rr2=sd; j2=e; }
            }
            i1=j1; i2=j2; r1=(float)rr1; r2=(float)rr2;
        }
        float m  = fmaxf(r1, r2);
        float e1 = expf(r1-m), e2 = expf(r2-m);
        float inv = 1.f/(e1+e2);
        float w1 = e1*inv, w2 = e2*inv;                // ROUTE_SCALE = 1
        bf16x8 ov;
        #pragma unroll
        for(int e=0;e<8;e++){
            float dv = (e==i1) ? w1 : ((e==i2) ? w2 : 0.f);
            ov[e] = f2bf(dv);
        }
        *(bf16x8*)(route + (pixbase + p)*8) = ov;
    }
}

// ---------------- main: bf16 MFMA, all 9 "experts" (8 + shared), fused per-pixel combine ----------------
// WG tile: 8 rows x 32 cols (256 px), 4 waves, wave = rows {2w,2w+1}.
// MFMA 32x32x16: A = weights (M=cout), B = x-patches (N=pixel col), K = tap*32+ci (tap-major).
__global__ __launch_bounds__(256, 2) void moe_main(const float* __restrict__ x,
                                                   const short* __restrict__ wt,
                                                   const short* __restrict__ route,
                                                   const float* __restrict__ eb,
                                                   const float* __restrict__ sb,
                                                   float* __restrict__ out){
    __shared__ __align__(16) short xt[10*4*34*8];   // [row 10][ci-chunk 4][px 34][8 ci] bf16
    __shared__ float ebs[288];                       // eb[8][32] then sb[32]
    int wg = blockIdx.x;
    int b  = wg >> 8;
    int y0 = ((wg >> 3) & 31) * 8;
    int x0 = (wg & 7) * 32;
    int t  = threadIdx.x;
    if(t < 256) ebs[t] = eb[t];
    if(t < 32)  ebs[256 + t] = sb[t];               // block is 256 threads: separate fill!

    const float* xim = x + (size_t)b*(32*256*256);
    // stage x tile (with halo) -> bf16 LDS; coalesced: lanes sweep px
    {
        int px = t & 31;
        #pragma unroll 4
        for(int i=0;i<40;i++){
            int pair = i*8 + (t>>5);                 // 0..319 = row*32+ci
            int row = pair >> 5, ci = pair & 31;
            int yy = y0 - 1 + row, xx = x0 - 1 + px;
            float v = (yy>=0 && yy<256 && xx>=0 && xx<256) ? xim[((size_t)ci*256+yy)*256+xx] : 0.f;
            xt[((row*4 + (ci>>3))*34 + px)*8 + (ci&7)] = f2bf(v);
        }
    }
    #pragma unroll
    for(int k=0;k<3;k++){                            // halo cols px=32,33 (640 elems)
        int p = t + k*256;
        if(p < 640){
            int pair = p >> 1, px = 32 + (p & 1);
            int row = pair >> 5, ci = pair & 31;
            int yy = y0 - 1 + row, xx = x0 - 1 + px;
            float v = (yy>=0 && yy<256 && xx>=0 && xx<256) ? xim[((size_t)ci*256+yy)*256+xx] : 0.f;
            xt[((row*4 + (ci>>3))*34 + px)*8 + (ci&7)] = f2bf(v);
        }
    }
    __syncthreads();

    int wv = t >> 6, l = t & 63, col = l & 31, hi = l >> 5;
    int c0 = hi * 4;                                  // C/D: col=lane&31, row=(r&3)+8*(r>>2)+4*hi

    bf16x8 rfrag[2];                                  // dense route weights for this wave's 2 rows
    #pragma unroll
    for(int ct=0; ct<2; ++ct){
        int yy = y0 + 2*wv + ct;
        size_t pix = (size_t)(b*256 + yy)*256 + x0 + col;
        rfrag[ct] = *(const bf16x8*)(route + pix*8);
    }

    float oa[2][16];
    #pragma unroll
    for(int r=0;r<16;r++){                            // init: shared bias
        int c = c0 + (r&3) + 8*(r>>2);
        float v = ebs[256 + c];
        oa[0][r] = v; oa[1][r] = v;
    }
    #pragma unroll
    for(int e=0;e<8;e++){                             // + sum_e d_e * expert_b[e][c]
        float d0 = bf2f(rfrag[0][e]);
        float d1 = bf2f(rfrag[1][e]);
        #pragma unroll
        for(int r=0;r<16;r++){
            int c = c0 + (r&3) + 8*(r>>2);
            float bv = ebs[e*32 + c];
            oa[0][r] = fmaf(d0, bv, oa[0][r]);
            oa[1][r] = fmaf(d1, bv, oa[1][r]);
        }
    }

    #pragma unroll
    for(int grp=0; grp<5; ++grp){                     // expert pairs {0,1}..{6,7}, then shared(e=8)
        const int  e0  = grp*2;
        const bool two = (grp < 4);
        f32x16 acc[2][2] = {};                        // [expert-in-pair][ct]
        #pragma unroll
        for(int s=0; s<18; ++s){                      // K=288: tap = s>>1, ci-half = s&1
            const int tap = s >> 1;
            const int kh = tap/3, kw = tap - kh*3;
            const int cib = (s&1)*16 + hi*8;          // A/B k = hi*8 + j
            const short* wp = wt + (((e0*9 + tap)*32 + col)*32 + cib);
            bf16x8 a0 = *(const bf16x8*)(wp);
            bf16x8 a1;
            if(two) a1 = *(const bf16x8*)(wp + 9*1024);
            const int chunk = (s&1)*2 + hi;
            #pragma unroll
            for(int ct=0; ct<2; ++ct){
                int rowi = 2*wv + ct + kh;
                bf16x8 bf = *(const bf16x8*)(&xt[((rowi*4 + chunk)*34 + (col + kw))*8]);
                acc[0][ct] = __builtin_amdgcn_mfma_f32_32x32x16_bf16(a0, bf, acc[0][ct], 0,0,0);
                if(two)
                    acc[1][ct] = __builtin_amdgcn_mfma_f32_32x32x16_bf16(a1, bf, acc[1][ct], 0,0,0);
            }
        }
        #pragma unroll
        for(int ct=0; ct<2; ++ct){
            if(two){
                float d0 = bf2f(rfrag[ct][e0]);
                float d1 = bf2f(rfrag[ct][e0+1]);
                #pragma unroll
                for(int r=0;r<16;r++)
                    oa[ct][r] += d0*acc[0][ct][r] + d1*acc[1][ct][r];
            } else {
                #pragma unroll
                for(int r=0;r<16;r++)
                    oa[ct][r] += acc[0][ct][r];       // shared expert, weight 1
            }
        }
    }

    float* ob = out + (size_t)b*(32*256*256);
    #pragma unroll
    for(int ct=0; ct<2; ++ct){
        int yy = y0 + 2*wv + ct;
        #pragma unroll
        for(int r=0;r<16;r++){
            int c = c0 + (r&3) + 8*(r>>2);
            ob[((size_t)c*256 + yy)*256 + x0 + col] = oa[ct][r];
        }
    }
}

extern "C" void kernel_launch(void* const* d_in, const int* in_sizes, int n_in,
                              void* d_out, int out_size, void* d_ws, size_t ws_size,
                              hipStream_t stream){
    (void)in_sizes; (void)n_in; (void)out_size; (void)ws_size;
    const float* x   = (const float*)d_in[0];
    const float* gw  = (const float*)d_in[1];
    const float* gb  = (const float*)d_in[2];
    const float* ew  = (const float*)d_in[3];
    const float* ebv = (const float*)d_in[4];
    const float* sw  = (const float*)d_in[5];
    const float* sbv = (const float*)d_in[6];
    float* out = (float*)d_out;

    short* route = (short*)d_ws;                          // 8*256*256 px * 8 bf16 = 8.39 MB
    short* wt    = route + (size_t)8*256*256*8;           // 9*9*32*32 bf16 = 166 KB

    prep_weights<<<dim3(324),  dim3(256), 0, stream>>>(ew, sw, wt);
    gate_kernel <<<dim3(512),  dim3(256), 0, stream>>>(x, gw, gb, route);
    moe_main    <<<dim3(2048), dim3(256), 0, stream>>>(x, wt, route, ebv, sbv, out);
}

// Round 3
// 431.409 us; speedup vs baseline: 2.3330x; 2.3330x over previous
//
#include <hip/hip_runtime.h>

typedef __attribute__((ext_vector_type(8)))  short bf16x8;   // 8 bf16 = 4 VGPR MFMA operand
typedef __attribute__((ext_vector_type(16))) float f32x16;   // 32x32 MFMA accumulator

__device__ __forceinline__ short f2bf(float f){
    unsigned int u = __builtin_bit_cast(unsigned int, f);
    u += 0x7fffu + ((u >> 16) & 1u);           // RNE, no NaN inputs here
    return (short)(u >> 16);
}
__device__ __forceinline__ float bf2f(short s){
    unsigned int u = ((unsigned int)(unsigned short)s) << 16;
    return __builtin_bit_cast(float, u);
}

// ---------------- prep: weights -> bf16 wt2[es(10)][tap(9)][cio(4)][cout(32)][8ci] ----------------
// es 0..7 = experts, es 8 = shared, es 9 = zeros (pad so every grp stages 36KB uniformly).
// Layout makes both LDS staging (linear) and A-frag ds_read_b128 lane-contiguous.
__global__ __launch_bounds__(256) void prep_weights(const float* __restrict__ ew,
                                                    const float* __restrict__ sw,
                                                    short* __restrict__ wt2){
    int i = blockIdx.x * 256 + threadIdx.x;      // 360 blocks * 256 = 92160 exactly
    int c7  = i & 7;
    int col = (i >> 3) & 31;                     // cout
    int cio = (i >> 8) & 3;                      // ci octet
    int rest = i >> 10;                          // 0..89
    int tap = rest % 9;
    int es  = rest / 9;                          // 0..9
    int ci  = cio*8 + c7;
    float v;
    if(es < 8)       v = ew[((es*32 + col)*32 + ci)*9 + tap];
    else if(es == 8) v = sw[(col*32 + ci)*9 + tap];
    else             v = 0.f;
    wt2[i] = f2bf(v);
}

// ---------------- gate: LDS-tiled fp32 conv -> sigmoid -> top2 -> softmax -> route ----------------
// 1024 WGs: 2 output rows per WG, 1 px per thread. x staged per-8ci-chunk into LDS fp32.
// Margin guard: if rank2-vs-rank3 biased margin < 1e-4, recompute scores in fp64 (rare).
__global__ __launch_bounds__(256) void gate_kernel(const float* __restrict__ x,
                                                   const float* __restrict__ gw,
                                                   const float* __restrict__ gb,
                                                   short* __restrict__ route){
    __shared__ float xs[32][264];                // [r4*8+ci][px+1] fp32, 33 KB
    int wg = blockIdx.x;                         // 1024 = 8 img * 128 row-pairs
    int b  = wg >> 7;
    int y0 = (wg & 127) * 2;
    int t  = threadIdx.x;
    int wv = t >> 6, lane = t & 63;
    const float* xim = x + (size_t)b * (32*256*256);

    float g[2][8];
    #pragma unroll
    for(int pr=0;pr<2;++pr)
        #pragma unroll
        for(int e=0;e<8;++e) g[pr][e] = 0.f;

    for(int cc=0; cc<4; ++cc){                   // ci chunks of 8
        __syncthreads();                         // prev chunk reads done
        #pragma unroll
        for(int sg=0; sg<8; ++sg){               // wave handles 8 of 32 segments
            int seg = wv*8 + sg;
            int r4  = seg >> 3;                  // 0..3 staged rows (y0-1 .. y0+2)
            int ci  = (seg & 7) + cc*8;
            int yy  = y0 - 1 + r4;
            bool rowok = (yy >= 0 && yy < 256);
            const float* xr = xim + ((size_t)ci*256 + yy)*256;
            #pragma unroll
            for(int i0=0; i0<5; ++i0){
                int i = i0*64 + lane;            // px+1 index, need < 258
                if(i < 258){
                    int xx = i - 1;
                    xs[seg][i] = (rowok && xx >= 0 && xx < 256) ? xr[xx] : 0.f;
                }
            }
        }
        __syncthreads();
        #pragma unroll
        for(int ci=0; ci<8; ++ci){
            float sv[4][3];
            #pragma unroll
            for(int r4=0;r4<4;++r4){
                sv[r4][0] = xs[r4*8+ci][t];
                sv[r4][1] = xs[r4*8+ci][t+1];
                sv[r4][2] = xs[r4*8+ci][t+2];
            }
            const float* gwp = gw + (cc*8 + ci)*9;     // gw[e][ci][kh][kw], e-stride 288
            #pragma unroll
            for(int e=0;e<8;++e){
                #pragma unroll
                for(int kh=0;kh<3;++kh){
                    #pragma unroll
                    for(int kw=0;kw<3;++kw){
                        float wval = gwp[e*288 + kh*3 + kw];
                        g[0][e] = fmaf(sv[kh][kw],   wval, g[0][e]);
                        g[1][e] = fmaf(sv[kh+1][kw], wval, g[1][e]);
                    }
                }
            }
        }
    }

    #pragma unroll
    for(int pr=0; pr<2; ++pr){
        float v1b=-1e30f, v2b=-1e30f, v3b=-1e30f, r1=0.f, r2=0.f; int i1=-1, i2=-1;
        #pragma unroll
        for(int e=0;e<8;e++){
            float se = 1.f/(1.f + expf(-g[pr][e]));
            float be = se + gb[e];
            if(be > v1b){ v3b=v2b; v2b=v1b; r2=r1; i2=i1; v1b=be; r1=se; i1=e; }
            else if(be > v2b){ v3b=v2b; v2b=be; r2=se; i2=e; }
            else if(be > v3b){ v3b=be; }
        }
        if(v2b - v3b < 1e-4f){                   // fp64 recompute (rare)
            int y = y0 + pr;
            double gd[8];
            #pragma unroll
            for(int e=0;e<8;e++) gd[e] = 0.0;
            for(int ci=0; ci<32; ++ci){
                for(int kh=0; kh<3; ++kh){
                    int yy = y + kh - 1;
                    if(yy < 0 || yy >= 256) continue;
                    const float* xr = xim + ((size_t)ci*256 + yy)*256;
                    for(int kw=0; kw<3; ++kw){
                        int xx = t + kw - 1;
                        if(xx < 0 || xx >= 256) continue;
                        double xv = (double)xr[xx];
                        const float* gwp = gw + ci*9 + kh*3 + kw;
                        #pragma unroll
                        for(int e=0;e<8;e++) gd[e] += xv * (double)gwp[e*288];
                    }
                }
            }
            double b1=-1e30, b2=-1e30; double rr1=0.0, rr2=0.0; int j1=-1, j2=-1;
            #pragma unroll
            for(int e=0;e<8;e++){
                double sd = 1.0/(1.0 + exp(-gd[e]));
                double bd = sd + (double)gb[e];
                if(bd > b1){ b2=b1; rr2=rr1; j2=j1; b1=bd; rr1=sd; j1=e; }
                else if(bd > b2){ b2=bd; rr2=sd; j2=e; }
            }
            i1=j1; i2=j2; r1=(float)rr1; r2=(float)rr2;
        }
        float m  = fmaxf(r1, r2);
        float e1 = expf(r1-m), e2 = expf(r2-m);
        float inv = 1.f/(e1+e2);
        float w1 = e1*inv, w2 = e2*inv;          // ROUTE_SCALE = 1
        bf16x8 ov;
        #pragma unroll
        for(int e=0;e<8;e++){
            float dv = (e==i1) ? w1 : ((e==i2) ? w2 : 0.f);
            ov[e] = f2bf(dv);
        }
        *(bf16x8*)(route + ((size_t)(b*256 + y0 + pr)*256 + t)*8) = ov;
    }
}

// ---------------- main: bf16 MFMA; weights LDS-staged per WG, x LDS tile, fused combine ----------------
// WG tile: 8 rows x 32 cols, 4 waves (2 rows each). MFMA 32x32x16: A=weights(M=cout), B=x(N=px).
// Per expert-pair grp: weights staged global->reg (prefetched during prev s-loop) ->LDS.
__global__ __launch_bounds__(256, 2) void moe_main(const float* __restrict__ x,
                                                   const short* __restrict__ wt2,
                                                   const short* __restrict__ route,
                                                   const float* __restrict__ eb,
                                                   const float* __restrict__ sb,
                                                   float* __restrict__ out){
    __shared__ __align__(16) short xt[10*4*34*8];    // [row10][cio4][px34][8ci] bf16, 21.76 KB
    __shared__ __align__(16) short wlds[18432];      // [e2][tap9][cio4][cout32][8ci] bf16, 36 KB
    __shared__ float ebs[288];                       // eb[8][32] then sb[32]
    int wg = blockIdx.x;
    int b  = wg >> 8;
    int y0 = ((wg >> 3) & 31) * 8;
    int x0 = (wg & 7) * 32;
    int t  = threadIdx.x;
    if(t < 256) ebs[t] = eb[t];
    if(t < 32)  ebs[256 + t] = sb[t];

    // prefetch grp0 weights into regs (latency overlaps x staging)
    bf16x8 wb[9];
    #pragma unroll
    for(int i=0;i<9;++i) wb[i] = *(const bf16x8*)(wt2 + i*2048 + t*8);

    const float* xim = x + (size_t)b*(32*256*256);
    {   // stage x tile (with halo) -> bf16 LDS
        int px = t & 31;
        #pragma unroll 4
        for(int i=0;i<40;i++){
            int pair = i*8 + (t>>5);                 // row*32+ci
            int row = pair >> 5, ci = pair & 31;
            int yy = y0 - 1 + row, xx = x0 - 1 + px;
            float v = (yy>=0 && yy<256 && xx>=0 && xx<256) ? xim[((size_t)ci*256+yy)*256+xx] : 0.f;
            xt[((row*4 + (ci>>3))*34 + px)*8 + (ci&7)] = f2bf(v);
        }
    }
    #pragma unroll
    for(int k=0;k<3;k++){                            // halo cols px=32,33
        int p = t + k*256;
        if(p < 640){
            int pair = p >> 1, px = 32 + (p & 1);
            int row = pair >> 5, ci = pair & 31;
            int yy = y0 - 1 + row, xx = x0 - 1 + px;
            float v = (yy>=0 && yy<256 && xx>=0 && xx<256) ? xim[((size_t)ci*256+yy)*256+xx] : 0.f;
            xt[((row*4 + (ci>>3))*34 + px)*8 + (ci&7)] = f2bf(v);
        }
    }
    __syncthreads();                                 // xt + ebs visible

    int wv = t >> 6, l = t & 63, col = l & 31, hi = l >> 5;
    int c0 = hi * 4;                                 // C/D: col=lane&31, row=(r&3)+8*(r>>2)+4*hi

    bf16x8 rfrag[2];
    #pragma unroll
    for(int ct=0; ct<2; ++ct){
        int yy = y0 + 2*wv + ct;
        size_t pix = (size_t)(b*256 + yy)*256 + x0 + col;
        rfrag[ct] = *(const bf16x8*)(route + pix*8);
    }

    float oa[2][16];
    #pragma unroll
    for(int r=0;r<16;r++){
        int c = c0 + (r&3) + 8*(r>>2);
        float v = ebs[256 + c];
        oa[0][r] = v; oa[1][r] = v;
    }
    #pragma unroll
    for(int e=0;e<8;e++){
        float d0 = bf2f(rfrag[0][e]);
        float d1 = bf2f(rfrag[1][e]);
        #pragma unroll
        for(int r=0;r<16;r++){
            int c = c0 + (r&3) + 8*(r>>2);
            float bv = ebs[e*32 + c];
            oa[0][r] = fmaf(d0, bv, oa[0][r]);
            oa[1][r] = fmaf(d1, bv, oa[1][r]);
        }
    }

    #pragma unroll
    for(int grp=0; grp<5; ++grp){                    // pairs {0,1}..{6,7}, then {shared, zero}
        const int  e0  = grp*2;
        const bool two = (grp < 4);
        __syncthreads();                             // wlds free (prev grp reads done)
        #pragma unroll
        for(int i=0;i<9;++i) *(bf16x8*)(&wlds[i*2048 + t*8]) = wb[i];
        __syncthreads();                             // staged visible
        if(grp < 4){                                 // prefetch next grp during s-loop
            const short* nb = wt2 + (grp+1)*18432;
            #pragma unroll
            for(int i=0;i<9;++i) wb[i] = *(const bf16x8*)(nb + i*2048 + t*8);
        }
        f32x16 acc[2][2] = {};                       // [expert-in-pair][ct]
        #pragma unroll
        for(int s=0; s<18; ++s){                     // K=288: tap=s>>1, ci-half=s&1
            const int tap = s >> 1;
            const int kh = tap/3, kw = tap - kh*3;
            const int cio = (s&1)*2 + hi;
            const int ai = ((tap*4 + cio)*32 + col)*8;
            bf16x8 a0 = *(const bf16x8*)(&wlds[ai]);
            bf16x8 a1;
            if(two) a1 = *(const bf16x8*)(&wlds[9216 + ai]);
            #pragma unroll
            for(int ct=0; ct<2; ++ct){
                int rowi = 2*wv + ct + kh;
                bf16x8 bf = *(const bf16x8*)(&xt[((rowi*4 + cio)*34 + (col + kw))*8]);
                acc[0][ct] = __builtin_amdgcn_mfma_f32_32x32x16_bf16(a0, bf, acc[0][ct], 0,0,0);
                if(two)
                    acc[1][ct] = __builtin_amdgcn_mfma_f32_32x32x16_bf16(a1, bf, acc[1][ct], 0,0,0);
            }
        }
        #pragma unroll
        for(int ct=0; ct<2; ++ct){
            if(two){
                float d0 = bf2f(rfrag[ct][e0]);
                float d1 = bf2f(rfrag[ct][e0+1]);
                #pragma unroll
                for(int r=0;r<16;r++)
                    oa[ct][r] += d0*acc[0][ct][r] + d1*acc[1][ct][r];
            } else {
                #pragma unroll
                for(int r=0;r<16;r++)
                    oa[ct][r] += acc[0][ct][r];       // shared expert, weight 1
            }
        }
    }

    float* ob = out + (size_t)b*(32*256*256);
    #pragma unroll
    for(int ct=0; ct<2; ++ct){
        int yy = y0 + 2*wv + ct;
        #pragma unroll
        for(int r=0;r<16;r++){
            int c = c0 + (r&3) + 8*(r>>2);
            ob[((size_t)c*256 + yy)*256 + x0 + col] = oa[ct][r];
        }
    }
}

extern "C" void kernel_launch(void* const* d_in, const int* in_sizes, int n_in,
                              void* d_out, int out_size, void* d_ws, size_t ws_size,
                              hipStream_t stream){
    (void)in_sizes; (void)n_in; (void)out_size; (void)ws_size;
    const float* x   = (const float*)d_in[0];
    const float* gw  = (const float*)d_in[1];
    const float* gb  = (const float*)d_in[2];
    const float* ew  = (const float*)d_in[3];
    const float* ebv = (const float*)d_in[4];
    const float* sw  = (const float*)d_in[5];
    const float* sbv = (const float*)d_in[6];
    float* out = (float*)d_out;

    short* route = (short*)d_ws;                          // 524288 px * 8 bf16 = 8.39 MB
    short* wt2   = route + (size_t)8*256*256*8;           // 92160 bf16 = 184 KB

    prep_weights<<<dim3(360),  dim3(256), 0, stream>>>(ew, sw, wt2);
    gate_kernel <<<dim3(1024), dim3(256), 0, stream>>>(x, gw, gb, route);
    moe_main    <<<dim3(2048), dim3(256), 0, stream>>>(x, wt2, route, ebv, sbv, out);
}

// Round 5
// 368.333 us; speedup vs baseline: 2.7325x; 1.1712x over previous
//
#include <hip/hip_runtime.h>

typedef __attribute__((ext_vector_type(8)))  short bf16x8;   // 8 bf16 = 4 VGPR MFMA operand
typedef __attribute__((ext_vector_type(16))) float f32x16;   // 32x32 MFMA accumulator

__device__ __forceinline__ short f2bf(float f){
    unsigned int u = __builtin_bit_cast(unsigned int, f);
    u += 0x7fffu + ((u >> 16) & 1u);           // RNE, no NaN inputs here
    return (short)(u >> 16);
}
__device__ __forceinline__ float bf2f(short s){
    unsigned int u = ((unsigned int)(unsigned short)s) << 16;
    return __builtin_bit_cast(float, u);
}

// async 16B global -> LDS (wave-uniform LDS base + lane*16 implicit)
__device__ __forceinline__ void glds16(const short* g, short* l){
    __builtin_amdgcn_global_load_lds(
        (const __attribute__((address_space(1))) unsigned int*)g,
        (__attribute__((address_space(3))) unsigned int*)l,
        16, 0, 0);
}

// ---------------- prep: weights -> bf16 wt2[es(10)][tap(9)][cio(4)][cout(32)][8ci] ----------------
__global__ __launch_bounds__(256) void prep_weights(const float* __restrict__ ew,
                                                    const float* __restrict__ sw,
                                                    short* __restrict__ wt2){
    int i = blockIdx.x * 256 + threadIdx.x;      // 360 blocks * 256 = 92160
    int c7  = i & 7;
    int col = (i >> 3) & 31;                     // cout
    int cio = (i >> 8) & 3;                      // ci octet
    int rest = i >> 10;                          // 0..89
    int tap = rest % 9;
    int es  = rest / 9;                          // 0..9
    int ci  = cio*8 + c7;
    float v;
    if(es < 8)       v = ew[((es*32 + col)*32 + ci)*9 + tap];
    else if(es == 8) v = sw[(col*32 + ci)*9 + tap];
    else             v = 0.f;
    wt2[i] = f2bf(v);
}

// ---------------- gate: LDS-tiled fp32 conv -> sigmoid -> top2 -> softmax -> route ----------------
__global__ __launch_bounds__(256) void gate_kernel(const float* __restrict__ x,
                                                   const float* __restrict__ gw,
                                                   const float* __restrict__ gb,
                                                   short* __restrict__ route){
    __shared__ float xs[32][272];                // [r4*8+ci][4+xx], 16B-aligned f4 slots, 34.8 KB
    int raw = blockIdx.x;                        // 1024; XCD chunk swizzle (1024%8==0)
    int wg  = (raw & 7)*128 + (raw >> 3);
    int b   = wg >> 7;
    int y0  = (wg & 127) * 2;
    int t   = threadIdx.x;
    int wv  = t >> 6, lane = t & 63;
    const float* xim = x + (size_t)b * (32*256*256);

    if(t < 64){                                  // edge zeros (xx=-1 -> [3], xx=256 -> [260]); persist
        int s2 = t >> 1;
        if(t & 1) xs[s2][260] = 0.f; else xs[s2][3] = 0.f;
    }

    float g[2][8];
    #pragma unroll
    for(int pr=0;pr<2;++pr)
        #pragma unroll
        for(int e=0;e<8;++e) g[pr][e] = 0.f;

    for(int cc=0; cc<4; ++cc){                   // ci chunks of 8
        __syncthreads();                         // prev chunk reads done (also covers edge zeros)
        #pragma unroll
        for(int sg=0; sg<8; ++sg){               // wave stages 8 of 32 segments via float4
            int seg = wv*8 + sg;
            int r4  = seg >> 3;                  // staged rows y0-1 .. y0+2
            int ci  = (seg & 7) + cc*8;
            int yy  = y0 - 1 + r4;
            const float* xr = xim + ((size_t)ci*256 + yy)*256;
            float4 v = make_float4(0.f,0.f,0.f,0.f);
            if(yy >= 0 && yy < 256) v = *(const float4*)(xr + lane*4);
            *(float4*)(&xs[seg][4 + lane*4]) = v;
        }
        __syncthreads();
        #pragma unroll
        for(int ci=0; ci<8; ++ci){
            float sv[4][3];
            #pragma unroll
            for(int r4=0;r4<4;++r4){
                sv[r4][0] = xs[r4*8+ci][t+3];    // xx = t-1+kw -> idx xx+4 = t+3+kw
                sv[r4][1] = xs[r4*8+ci][t+4];
                sv[r4][2] = xs[r4*8+ci][t+5];
            }
            const float* gwp = gw + (cc*8 + ci)*9;     // gw[e][ci][kh][kw], e-stride 288
            #pragma unroll
            for(int e=0;e<8;++e){
                #pragma unroll
                for(int kh=0;kh<3;++kh){
                    #pragma unroll
                    for(int kw=0;kw<3;++kw){
                        float wval = gwp[e*288 + kh*3 + kw];
                        g[0][e] = fmaf(sv[kh][kw],   wval, g[0][e]);
                        g[1][e] = fmaf(sv[kh+1][kw], wval, g[1][e]);
                    }
                }
            }
        }
    }

    #pragma unroll
    for(int pr=0; pr<2; ++pr){
        float v1b=-1e30f, v2b=-1e30f, v3b=-1e30f, r1=0.f, r2=0.f; int i1=-1, i2=-1;
        #pragma unroll
        for(int e=0;e<8;e++){
            float se = 1.f/(1.f + expf(-g[pr][e]));
            float be = se + gb[e];
            if(be > v1b){ v3b=v2b; v2b=v1b; r2=r1; i2=i1; v1b=be; r1=se; i1=e; }
            else if(be > v2b){ v3b=v2b; v2b=be; r2=se; i2=e; }
            else if(be > v3b){ v3b=be; }
        }
        if(v2b - v3b < 2e-5f){                   // fp64 recompute (rare)
            int y = y0 + pr;
            double gd[8];
            #pragma unroll
            for(int e=0;e<8;e++) gd[e] = 0.0;
            for(int ci=0; ci<32; ++ci){
                for(int kh=0; kh<3; ++kh){
                    int yy = y + kh - 1;
                    if(yy < 0 || yy >= 256) continue;
                    const float* xr = xim + ((size_t)ci*256 + yy)*256;
                    for(int kw=0; kw<3; ++kw){
                        int xx = t + kw - 1;
                        if(xx < 0 || xx >= 256) continue;
                        double xv = (double)xr[xx];
                        const float* gwp = gw + ci*9 + kh*3 + kw;
                        #pragma unroll
                        for(int e=0;e<8;e++) gd[e] += xv * (double)gwp[e*288];
                    }
                }
            }
            double b1=-1e30, b2=-1e30; double rr1=0.0, rr2=0.0; int j1=-1, j2=-1;
            #pragma unroll
            for(int e=0;e<8;e++){
                double sd = 1.0/(1.0 + exp(-gd[e]));
                double bd = sd + (double)gb[e];
                if(bd > b1){ b2=b1; rr2=rr1; j2=j1; b1=bd; rr1=sd; j1=e; }
                else if(bd > b2){ b2=bd; rr2=sd; j2=e; }
            }
            i1=j1; i2=j2; r1=(float)rr1; r2=(float)rr2;
        }
        float m  = fmaxf(r1, r2);
        float e1 = expf(r1-m), e2 = expf(r2-m);
        float inv = 1.f/(e1+e2);
        float w1 = e1*inv, w2 = e2*inv;          // ROUTE_SCALE = 1
        bf16x8 ov;
        #pragma unroll
        for(int e=0;e<8;e++){
            float dv = (e==i1) ? w1 : ((e==i2) ? w2 : 0.f);
            ov[e] = f2bf(dv);
        }
        *(bf16x8*)(route + ((size_t)(b*256 + y0 + pr)*256 + t)*8) = ov;
    }
}

// ---------------- main: bf16 MFMA; expert-at-a-time, glds-double-buffered weights ----------------
// WG tile: 8 rows x 32 cols, 4 waves (2 rows each). MFMA 32x32x16: A=weights(M=cout), B=x(N=px).
__global__ __launch_bounds__(256, 4) void moe_main(const float* __restrict__ x,
                                                   const short* __restrict__ wt2,
                                                   const short* __restrict__ route,
                                                   const float* __restrict__ eb,
                                                   const float* __restrict__ sb,
                                                   float* __restrict__ out){
    __shared__ __align__(16) short xt[10*4*34*8];    // [row10][cio4][px34][8ci] bf16, 21.76 KB
    __shared__ __align__(16) short wlds[2*9216];     // dbuf: [tap9][cio4][cout32][8ci] bf16, 2x18 KB
    __shared__ float ebs[288];                       // eb[8][32] then sb[32]
    int raw = blockIdx.x;                            // 2048; XCD chunk swizzle -> 1 image per XCD
    int wg  = (raw & 7)*256 + (raw >> 3);
    int b   = wg >> 8;
    int y0  = ((wg >> 3) & 31) * 8;
    int x0  = (wg & 7) * 32;
    int t   = threadIdx.x;
    int wv  = t >> 6, l = t & 63, col = l & 31, hi = l >> 5;
    if(t < 256) ebs[t] = eb[t];
    if(t < 32)  ebs[256 + t] = sb[t];

    // issue async stage of expert 0 -> buf0 (overlaps x staging)
    #pragma unroll
    for(int j=0;j<5;++j){
        int chunk = wv + 4*j;                        // wave-uniform predicate
        if(chunk < 18) glds16(wt2 + chunk*512 + l*8, wlds + chunk*512);
    }

    const float* xim = x + (size_t)b*(32*256*256);
    {   // stage x tile (with halo) -> bf16 LDS
        int px = t & 31;
        #pragma unroll 4
        for(int i=0;i<40;i++){
            int pair = i*8 + (t>>5);                 // row*32+ci
            int row = pair >> 5, ci = pair & 31;
            int yy = y0 - 1 + row, xx = x0 - 1 + px;
            float v = (yy>=0 && yy<256 && xx>=0 && xx<256) ? xim[((size_t)ci*256+yy)*256+xx] : 0.f;
            xt[((row*4 + (ci>>3))*34 + px)*8 + (ci&7)] = f2bf(v);
        }
    }
    #pragma unroll
    for(int k=0;k<3;k++){                            // halo cols px=32,33
        int p = t + k*256;
        if(p < 640){
            int pair = p >> 1, px = 32 + (p & 1);
            int row = pair >> 5, ci = pair & 31;
            int yy = y0 - 1 + row, xx = x0 - 1 + px;
            float v = (yy>=0 && yy<256 && xx>=0 && xx<256) ? xim[((size_t)ci*256+yy)*256+xx] : 0.f;
            xt[((row*4 + (ci>>3))*34 + px)*8 + (ci&7)] = f2bf(v);
        }
    }
    asm volatile("s_waitcnt vmcnt(0)" ::: "memory");
    __syncthreads();                                 // xt + ebs + expert0 staged

    int c0 = hi * 4;                                 // C/D: col=lane&31, row=(r&3)+8*(r>>2)+4*hi

    bf16x8 rfrag[2];
    #pragma unroll
    for(int ct=0; ct<2; ++ct){
        int yy = y0 + 2*wv + ct;
        size_t pix = (size_t)(b*256 + yy)*256 + x0 + col;
        rfrag[ct] = *(const bf16x8*)(route + pix*8);
    }

    float oa[2][16];
    #pragma unroll
    for(int r=0;r<16;r++){
        int c = c0 + (r&3) + 8*(r>>2);
        float v = ebs[256 + c];
        oa[0][r] = v; oa[1][r] = v;
    }
    #pragma unroll
    for(int e=0;e<8;e++){
        float d0 = bf2f(rfrag[0][e]);
        float d1 = bf2f(rfrag[1][e]);
        #pragma unroll
        for(int r=0;r<16;r++){
            int c = c0 + (r&3) + 8*(r>>2);
            float bv = ebs[e*32 + c];
            oa[0][r] = fmaf(d0, bv, oa[0][r]);
            oa[1][r] = fmaf(d1, bv, oa[1][r]);
        }
    }

    #pragma unroll
    for(int e=0; e<9; ++e){                          // experts 0..7, then shared (8)
        const int cur = e & 1;
        if(e){
            asm volatile("s_waitcnt vmcnt(0)" ::: "memory");
            __syncthreads();                         // buf[cur] staged; prev reads of it done
        }
        if(e < 8){                                   // issue next expert -> other buffer
            const short* src = wt2 + (e+1)*9216;
            short* dst = wlds + (cur^1)*9216;
            #pragma unroll
            for(int j=0;j<5;++j){
                int chunk = wv + 4*j;
                if(chunk < 18) glds16(src + chunk*512 + l*8, dst + chunk*512);
            }
        }
        f32x16 acc[2] = {};
        #pragma unroll
        for(int s=0; s<18; ++s){                     // K=288: tap=s>>1, ci-half=s&1
            const int tap = s >> 1;
            const int kh = tap/3, kw = tap - kh*3;
            const int cio = (s&1)*2 + hi;
            bf16x8 a0 = *(const bf16x8*)(&wlds[cur*9216 + ((tap*4+cio)*32 + col)*8]);
            #pragma unroll
            for(int ct=0; ct<2; ++ct){
                int rowi = 2*wv + ct + kh;
                bf16x8 bf = *(const bf16x8*)(&xt[((rowi*4 + cio)*34 + (col + kw))*8]);
                acc[ct] = __builtin_amdgcn_mfma_f32_32x32x16_bf16(a0, bf, acc[ct], 0,0,0);
            }
        }
        if(e < 8){
            #pragma unroll
            for(int ct=0; ct<2; ++ct){
                float d = bf2f(rfrag[ct][e]);
                #pragma unroll
                for(int r=0;r<16;r++) oa[ct][r] += d*acc[ct][r];
            }
        } else {
            #pragma unroll
            for(int ct=0; ct<2; ++ct)
                #pragma unroll
                for(int r=0;r<16;r++) oa[ct][r] += acc[ct][r];
        }
    }

    float* ob = out + (size_t)b*(32*256*256);
    #pragma unroll
    for(int ct=0; ct<2; ++ct){
        int yy = y0 + 2*wv + ct;
        #pragma unroll
        for(int r=0;r<16;r++){
            int c = c0 + (r&3) + 8*(r>>2);
            __builtin_nontemporal_store(oa[ct][r], &ob[((size_t)c*256 + yy)*256 + x0 + col]);
        }
    }
}

extern "C" void kernel_launch(void* const* d_in, const int* in_sizes, int n_in,
                              void* d_out, int out_size, void* d_ws, size_t ws_size,
                              hipStream_t stream){
    (void)in_sizes; (void)n_in; (void)out_size; (void)ws_size;
    const float* x   = (const float*)d_in[0];
    const float* gw  = (const float*)d_in[1];
    const float* gb  = (const float*)d_in[2];
    const float* ew  = (const float*)d_in[3];
    const float* ebv = (const float*)d_in[4];
    const float* sw  = (const float*)d_in[5];
    const float* sbv = (const float*)d_in[6];
    float* out = (float*)d_out;

    short* route = (short*)d_ws;                          // 524288 px * 8 bf16 = 8.39 MB
    short* wt2   = route + (size_t)8*256*256*8;           // 92160 bf16 = 184 KB

    prep_weights<<<dim3(360),  dim3(256), 0, stream>>>(ew, sw, wt2);
    gate_kernel <<<dim3(1024), dim3(256), 0, stream>>>(x, gw, gb, route);
    moe_main    <<<dim3(2048), dim3(256), 0, stream>>>(x, wt2, route, ebv, sbv, out);
}